// Round 4
// baseline (449.662 us; speedup 1.0000x reference)
//
#include <hip/hip_runtime.h>
#include <hip/hip_bf16.h>

// All tensors are float32, matching the reference dtypes.

// ws layout (float offsets), total 126208 floats = 504832 bytes:
//   obs_ws  2x8192    @ 0       gathered obs rows t=9 (row0), t=10 (row1)
//   spT     256x12    @ 16384   sp hidden transposed: spT[k][t]
//   tp_h    256       @ 19456
//   h1      2x2048    @ 19712   fc1 raw (pre-bias) rows t=9,10
//   h2      2x2048    @ 23808
//   h3      2x12288   @ 27904
//   part    <=73728   @ 52480   split-K partials (dead before U/Y written)
//   U       3x1024x12 @ 52480   U[a'][n][t], a'=a-9, a in {9,10,11}  (reuses part)
//   Y       3x1024x12 @ 89344   path0=X9@Wf1, path1=X10@(Wf0+Wb0), path2=X9@Wb1

#define OFF_OBS   0
#define OFF_SPT   16384
#define OFF_TPH   19456
#define OFF_H1    19712
#define OFF_H2    23808
#define OFF_H3    27904
#define OFF_PART  52480
#define OFF_U     52480
#define OFF_Y     89344

// ---------------------------------------------------------------------------
// hidden: sp hidden (12x256, blocks 0..11), tp hidden (block 12),
// obs row gather (blocks 13,14).
__global__ void k_hidden(const float* __restrict__ li, const float* __restrict__ gs_w1,
                         const float* __restrict__ gs_b1, const float* __restrict__ tf,
                         const float* __restrict__ gt_w1, const float* __restrict__ gt_b1,
                         const float* __restrict__ obs,
                         float* __restrict__ obs_ws, float* __restrict__ spT,
                         float* __restrict__ tp_h)
{
  int b = blockIdx.x, tid = threadIdx.x;
  if (b < 12) {
    float acc = 0.f;
    for (int k = 0; k < 1024; ++k)
      acc = fmaf(li[b*1024 + k], gs_w1[k*256 + tid], acc);
    float v = acc + gs_b1[tid];
    spT[tid*12 + b] = v > 0.f ? v : 0.f;
  } else if (b == 12) {
    float acc = 0.f;
    for (int k = 0; k < 36; ++k)
      acc = fmaf(tf[k], gt_w1[k*256 + tid], acc);
    float v = acc + gt_b1[tid];
    tp_h[tid] = v > 0.f ? v : 0.f;
  } else {
    int tp = b - 13;  // 0 -> t=9, 1 -> t=10
    for (int k = tid; k < 8192; k += 256) {
      int n = k >> 3, d = k & 7;
      obs_ws[tp*8192 + k] = obs[n*96 + d*12 + 9 + tp];
    }
  }
}

// ---------------------------------------------------------------------------
// 2-row GEMM, split-K, plain partial stores (no atomics, no pre-zero needed).
// 256 threads = 8 k-groups x 32 col-groups (4 cols each) -> 128 cols/block.
// part[(t*N + col)*P + blockIdx.y] = partial over K-chunk blockIdx.y.
template<int KS>
__global__ void k_gemm2(const float* __restrict__ xin, const float* __restrict__ bias_in,
                        const float* __restrict__ W, float* __restrict__ part,
                        int N, int K, int P)
{
  __shared__ float lx[2*KS];
  __shared__ float red[8][32][8];
  int tid = threadIdx.x;
  int k0 = blockIdx.y * KS;
  for (int i = tid; i < 2*KS; i += 256) {
    int t = i / KS, kk = i - t*KS;
    float v = xin[t*K + k0 + kk];
    if (bias_in) { v += bias_in[k0 + kk]; v = v > 0.f ? v : 0.f; }
    lx[i] = v;
  }
  __syncthreads();
  int kg = tid >> 5, cg = tid & 31;
  int colbase = blockIdx.x*128 + cg*4;
  float a0=0,a1=0,a2=0,a3=0,c0=0,c1=0,c2=0,c3=0;
  const int ksub = KS/8;
  for (int kk = kg*ksub; kk < kg*ksub + ksub; ++kk) {
    float4 w = *(const float4*)(W + (size_t)(k0+kk)*N + colbase);
    float x0 = lx[kk], x1 = lx[KS + kk];
    a0=fmaf(x0,w.x,a0); a1=fmaf(x0,w.y,a1); a2=fmaf(x0,w.z,a2); a3=fmaf(x0,w.w,a3);
    c0=fmaf(x1,w.x,c0); c1=fmaf(x1,w.y,c1); c2=fmaf(x1,w.z,c2); c3=fmaf(x1,w.w,c3);
  }
  float* rp = &red[kg][cg][0];
  rp[0]=a0; rp[1]=a1; rp[2]=a2; rp[3]=a3; rp[4]=c0; rp[5]=c1; rp[6]=c2; rp[7]=c3;
  __syncthreads();
  int cg2 = tid & 31, q = tid >> 5;
  float s = 0.f;
  #pragma unroll
  for (int g = 0; g < 8; ++g) s += red[g][cg2][q];
  int t = q >> 2, c = q & 3;
  part[(size_t)(t*N + blockIdx.x*128 + cg2*4 + c)*P + blockIdx.y] = s;
}

// reduce P partials per element
__global__ void k_red(const float* __restrict__ part, float* __restrict__ outp,
                      int M, int P)
{
  int i = blockIdx.x*256 + threadIdx.x;
  if (i < M) {
    float s = 0.f;
    for (int p = 0; p < P; ++p) s += part[(size_t)i*P + p];
    outp[i] = s;
  }
}

// ---------------------------------------------------------------------------
// U columns for a in {9,10,11}: U[a'][n][t] = relu(spT[:,t].gs_w2[:,c]+gs_b2[c])
//                                           + relu(tp_h.gt_w2[:,c]+gt_b2[c]), c=n*12+9+a'
__global__ void k_U(const float* __restrict__ spT, const float* __restrict__ tp_h,
                    const float* __restrict__ gs_w2, const float* __restrict__ gs_b2,
                    const float* __restrict__ gt_w2, const float* __restrict__ gt_b2,
                    float* __restrict__ U)
{
  int idx = blockIdx.x*128 + threadIdx.x;  // 0..3071
  int n = idx / 3, ap = idx - n*3;
  int c = n*12 + 9 + ap;
  float acc[12];
  #pragma unroll
  for (int t=0;t<12;++t) acc[t]=0.f;
  float acct = 0.f;
  for (int k = 0; k < 256; ++k) {
    float w = gs_w2[(size_t)k*12288 + c];
    #pragma unroll
    for (int t=0;t<12;++t) acc[t] = fmaf(spT[k*12+t], w, acc[t]);
    acct = fmaf(tp_h[k], gt_w2[(size_t)k*12288 + c], acct);
  }
  float tpv = acct + gt_b2[c]; tpv = tpv>0.f ? tpv : 0.f;
  float gb = gs_b2[c];
  #pragma unroll
  for (int t=0;t<12;++t) {
    float v = acc[t] + gb; v = v>0.f ? v : 0.f;
    U[ap*12288 + n*12 + t] = v + tpv;
  }
}

// ---------------------------------------------------------------------------
// Y precompute: X9/X10 = relu(h3 + b3); three per-node 12x12 products.
__global__ void k_Y(const float* __restrict__ h3, const float* __restrict__ b3,
                    const float* __restrict__ Wf, const float* __restrict__ Wb,
                    float* __restrict__ Y)
{
  __shared__ float Ws0[144], Ws1[144], Ws2[144];
  int tid = threadIdx.x;
  if (tid < 144) {
    Ws0[tid] = Wf[144 + tid];          // Wf[1]       (path 0, L(9,10))
    Ws1[tid] = Wf[tid] + Wb[tid];      // Wf[0]+Wb[0] (path 1, L(10,10))
    Ws2[tid] = Wb[144 + tid];          // Wb[1]       (path 2, L(11,10))
  }
  __syncthreads();
  int n = blockIdx.x*256 + tid;
  float X9[12], X10[12];
  #pragma unroll
  for (int f=0; f<12; ++f) {
    float bb = b3[n*12 + f];
    float v9  = h3[n*12 + f] + bb;          X9[f]  = v9  > 0.f ? v9  : 0.f;
    float v10 = h3[12288 + n*12 + f] + bb;  X10[f] = v10 > 0.f ? v10 : 0.f;
  }
  #pragma unroll
  for (int g=0; g<12; ++g) {
    float y0=0.f, y1=0.f, y2=0.f;
    #pragma unroll
    for (int f=0; f<12; ++f) {
      y0 = fmaf(X9[f],  Ws0[f*12+g], y0);
      y1 = fmaf(X10[f], Ws1[f*12+g], y1);
      y2 = fmaf(X9[f],  Ws2[f*12+g], y2);
    }
    Y[n*12 + g]         = y0;
    Y[12288 + n*12 + g] = y1;
    Y[24576 + n*12 + g] = y2;
  }
}

// ---------------------------------------------------------------------------
// Fused scores -> threshold -> softmax -> weighted sum. ONE output row per block.
// Pair ap: 0 -> L(9,10) w/ Y0; 1 -> L(10,10) w/ Y1; 2 -> L(11,10) w/ Y2.
#define SS 1032  // LDS row stride
__global__ void __launch_bounds__(256) k_final(
    const float* __restrict__ U, const float* __restrict__ Y,
    const float* __restrict__ Bm, const float* __restrict__ bvec,
    float* __restrict__ out)
{
  __shared__ float sc[3*SS];
  __shared__ float P[3][12];
  __shared__ float invS[3];
  __shared__ float Bl[144];
  __shared__ float bl[12];
  int tid = threadIdx.x;
  int row = blockIdx.x;
  if (tid < 144) Bl[tid] = Bm[tid];
  if (tid < 12)  bl[tid] = bvec[tid];
  __syncthreads();
  if (tid < 36) {  // P[ap][j] = sum_t U[ap][row][t] * B[t][j]
    int ap = tid / 12, j = tid % 12;
    float s = 0.f;
    #pragma unroll
    for (int t=0;t<12;++t)
      s = fmaf(U[ap*12288 + row*12 + t], Bl[t*12 + j], s);
    P[ap][j] = s;
  }
  __syncthreads();
  const float* U10 = U + 12288;
  for (int jj = 0; jj < 4; ++jj) {
    int j = tid + jj*256;
    float u[12];
    #pragma unroll
    for (int t=0;t<12;++t) u[t] = U10[j*12 + t];
    #pragma unroll
    for (int ap=0;ap<3;++ap) {
      float s = 0.f;
      #pragma unroll
      for (int t=0;t<12;++t) s = fmaf(P[ap][t], u[t], s);
      sc[ap*SS + j] = (s >= 0.05f) ? s : 0.f;
    }
  }
  __syncthreads();
  int wv = tid >> 6, ln = tid & 63;
  if (wv < 3) {  // wave wv owns pair wv: row softmax over 1024
    float m = -1e30f;
    for (int q = 0; q < 16; ++q) m = fmaxf(m, sc[wv*SS + ln + q*64]);
    #pragma unroll
    for (int o = 32; o > 0; o >>= 1) m = fmaxf(m, __shfl_xor(m, o));
    float sum = 0.f;
    for (int q = 0; q < 16; ++q) {
      int j = ln + q*64;
      float e = __expf(sc[wv*SS + j] - m);
      sc[wv*SS + j] = e;
      sum += e;
    }
    #pragma unroll
    for (int o = 32; o > 0; o >>= 1) sum += __shfl_xor(sum, o);
    if (ln == 0) invS[wv] = 1.f / sum;
  }
  __syncthreads();
  float acc[12];
  #pragma unroll
  for (int f=0;f<12;++f) acc[f]=0.f;
  if (wv < 3) {  // weighted sum: sum_j exp * Y[path wv][j][:]
    for (int q = 0; q < 16; ++q) {
      int j = ln + q*64;
      float e = sc[wv*SS + j];
      const float* yr = Y + wv*12288 + j*12;
      #pragma unroll
      for (int f=0;f<12;++f) acc[f] = fmaf(e, yr[f], acc[f]);
    }
  }
  __syncthreads();  // exps consumed; reuse sc as reduction buffer (needs 2304)
  float* red = sc;
  if (wv < 3) {
    #pragma unroll
    for (int f=0;f<12;++f) red[(wv*12 + f)*64 + ln] = acc[f];
  }
  __syncthreads();
  if (tid < 12) {
    int f = tid;
    float s0=0.f, s1=0.f, s2=0.f;
    for (int g = 0; g < 64; ++g) {
      s0 += red[(0*12+f)*64 + g];
      s1 += red[(1*12+f)*64 + g];
      s2 += red[(2*12+f)*64 + g];
    }
    float a1v = invS[1]*s1;                 // L(10,10) @ X10 @ (Wf0+Wb0)
    float a2v = invS[0]*s0 + invS[2]*s2;    // L(9,10)@X9@Wf1 + L(11,10)@X9@Wb1
    float v1 = a1v + bl[f]; v1 = v1>0.f ? v1 : 0.f;
    float v2 = a2v + bl[f]; v2 = v2>0.f ? v2 : 0.f;
    out[row*12 + f] = v1 + v2;
  }
}

extern "C" void kernel_launch(void* const* d_in, const int* in_sizes, int n_in,
                              void* d_out, int out_size, void* d_ws, size_t ws_size,
                              hipStream_t stream)
{
  const float* obs   = (const float*)d_in[0];
  const float* tf    = (const float*)d_in[1];
  const float* fc_w1 = (const float*)d_in[2];
  const float* fc_b1 = (const float*)d_in[3];
  const float* fc_w2 = (const float*)d_in[4];
  const float* fc_b2 = (const float*)d_in[5];
  const float* fc_w3 = (const float*)d_in[6];
  const float* fc_b3 = (const float*)d_in[7];
  const float* Wf    = (const float*)d_in[8];
  const float* Wb    = (const float*)d_in[9];
  const float* bvec  = (const float*)d_in[10];
  const float* li    = (const float*)d_in[11];
  const float* gs_w1 = (const float*)d_in[12];
  const float* gs_b1 = (const float*)d_in[13];
  const float* gs_w2 = (const float*)d_in[14];
  const float* gs_b2 = (const float*)d_in[15];
  const float* gt_w1 = (const float*)d_in[16];
  const float* gt_b1 = (const float*)d_in[17];
  const float* gt_w2 = (const float*)d_in[18];
  const float* gt_b2 = (const float*)d_in[19];
  const float* Bm    = (const float*)d_in[20];
  float* out = (float*)d_out;
  float* ws  = (float*)d_ws;

  float* obs_ws = ws + OFF_OBS;
  float* spT    = ws + OFF_SPT;
  float* tp_h   = ws + OFF_TPH;
  float* h1     = ws + OFF_H1;
  float* h2     = ws + OFF_H2;
  float* h3     = ws + OFF_H3;
  float* part   = ws + OFF_PART;
  float* U      = ws + OFF_U;
  float* Y      = ws + OFF_Y;

  // zero all four outputs (outputs 1..3 are exactly zero; output 0 overwritten)
  hipMemsetAsync(d_out, 0, (size_t)out_size * sizeof(float), stream);

  k_hidden<<<dim3(15), dim3(256), 0, stream>>>(li, gs_w1, gs_b1, tf, gt_w1, gt_b1,
                                               obs, obs_ws, spT, tp_h);
  // fc1: (2x8192)@(8192x2048), split K into 16 chunks of 512 -> 256 blocks
  k_gemm2<512><<<dim3(16,16), dim3(256), 0, stream>>>(obs_ws, (const float*)nullptr,
                                                      fc_w1, part, 2048, 8192, 16);
  k_red<<<dim3(16), dim3(256), 0, stream>>>(part, h1, 4096, 16);
  // fc2: (2x2048)@(2048x2048), K chunks of 256
  k_gemm2<256><<<dim3(16,8), dim3(256), 0, stream>>>(h1, fc_b1, fc_w2, part,
                                                     2048, 2048, 8);
  k_red<<<dim3(16), dim3(256), 0, stream>>>(part, h2, 4096, 8);
  // fc3: (2x2048)@(2048x12288), K chunks of 1024 (part fits the 73728 window)
  k_gemm2<1024><<<dim3(96,2), dim3(256), 0, stream>>>(h2, fc_b2, fc_w3, part,
                                                      12288, 2048, 2);
  k_red<<<dim3(96), dim3(256), 0, stream>>>(part, h3, 24576, 2);

  k_U<<<dim3(24), dim3(128), 0, stream>>>(spT, tp_h, gs_w2, gs_b2, gt_w2, gt_b2, U);
  k_Y<<<dim3(4), dim3(256), 0, stream>>>(h3, fc_b3, Wf, Wb, Y);
  k_final<<<dim3(1024), dim3(256), 0, stream>>>(U, Y, Bm, bvec, out);
}

// Round 5
// 385.953 us; speedup vs baseline: 1.1651x; 1.1651x over previous
//
#include <hip/hip_runtime.h>
#include <hip/hip_bf16.h>

// All tensors are float32.

// ws layout (float offsets), total 126208 floats = 504832 bytes (same as R4):
//   obs_ws  2x8192    @ 0       gathered obs rows t=9 (row0), t=10 (row1)
//   sp_pre  12x256    @ 16384   raw sp hidden (pre-bias/relu), atomic accum
//   tp_h    256       @ 19456   tp hidden (post-relu)
//   h1      2x2048    @ 19712   fc1 raw rows t=9,10
//   h2      2x2048    @ 23808
//   h3      2x12288   @ 27904
//   part    <=73728   @ 52480   fc split-K partials (dead before U written)
//   U       3x1024x12 @ 52480   U[ap][n][t] raw then in-place finalized
//   tp_pre  1024x3    @ 89344   raw tp second-layer (dead before Y written)
//   Y       3x1024x12 @ 89344   path0=X9@Wf1, path1=X10@(Wf0+Wb0), path2=X9@Wb1

#define OFF_OBS   0
#define OFF_SPPRE 16384
#define OFF_TPH   19456
#define OFF_H1    19712
#define OFF_H2    23808
#define OFF_H3    27904
#define OFF_PART  52480
#define OFF_U     52480
#define OFF_TPPRE 89344
#define OFF_Y     89344

// ---------------------------------------------------------------------------
// hidden: blocks 0..15: sp first-layer GEMM (2 col-chunks x 8 k-chunks),
// atomic into sp_pre. block 16: tp hidden. blocks 17..24: obs gather.
__global__ void k_hidden(const float* __restrict__ li, const float* __restrict__ gs_w1,
                         const float* __restrict__ tf,  const float* __restrict__ gt_w1,
                         const float* __restrict__ gt_b1, const float* __restrict__ obs,
                         float* __restrict__ obs_ws, float* __restrict__ sp_pre,
                         float* __restrict__ tp_h)
{
  int b = blockIdx.x, tid = threadIdx.x;
  if (b < 16) {
    __shared__ float lil[12][128];
    int cb = b & 1, kc = b >> 1;           // col chunk (128), k chunk (128)
    for (int i = tid; i < 1536; i += 256) {
      int bb = i >> 7, kk = i & 127;
      lil[bb][kk] = li[bb*1024 + kc*128 + kk];
    }
    __syncthreads();
    int col = cb*128 + (tid & 127);
    int kh = tid >> 7;                      // 0/1: k-half of 64
    float acc[12];
    #pragma unroll
    for (int t=0;t<12;++t) acc[t]=0.f;
    for (int kk = kh*64; kk < kh*64 + 64; ++kk) {
      float w = gs_w1[(size_t)(kc*128 + kk)*256 + col];
      #pragma unroll
      for (int t=0;t<12;++t) acc[t] = fmaf(lil[t][kk], w, acc[t]);
    }
    #pragma unroll
    for (int t=0;t<12;++t) atomicAdd(&sp_pre[t*256 + col], acc[t]);
  } else if (b == 16) {
    float acc = 0.f;
    for (int k = 0; k < 36; ++k)
      acc = fmaf(tf[k], gt_w1[k*256 + tid], acc);
    float v = acc + gt_b1[tid];
    tp_h[tid] = v > 0.f ? v : 0.f;
  } else {
    int g = b - 17;                         // 0..7
    for (int i = tid; i < 2048; i += 256) {
      int e = g*2048 + i;
      int tp = e >> 13, k = e & 8191;
      int n = k >> 3, d = k & 7;
      obs_ws[e] = obs[n*96 + d*12 + 9 + tp];
    }
  }
}

// ---------------------------------------------------------------------------
// 2-row GEMM, split-K, plain partial stores.
template<int KS>
__global__ void k_gemm2(const float* __restrict__ xin, const float* __restrict__ bias_in,
                        const float* __restrict__ W, float* __restrict__ part,
                        int N, int K, int P)
{
  __shared__ float lx[2*KS];
  __shared__ float red[8][32][8];
  int tid = threadIdx.x;
  int k0 = blockIdx.y * KS;
  for (int i = tid; i < 2*KS; i += 256) {
    int t = i / KS, kk = i - t*KS;
    float v = xin[t*K + k0 + kk];
    if (bias_in) { v += bias_in[k0 + kk]; v = v > 0.f ? v : 0.f; }
    lx[i] = v;
  }
  __syncthreads();
  int kg = tid >> 5, cg = tid & 31;
  int colbase = blockIdx.x*128 + cg*4;
  float a0=0,a1=0,a2=0,a3=0,c0=0,c1=0,c2=0,c3=0;
  const int ksub = KS/8;
  for (int kk = kg*ksub; kk < kg*ksub + ksub; ++kk) {
    float4 w = *(const float4*)(W + (size_t)(k0+kk)*N + colbase);
    float x0 = lx[kk], x1 = lx[KS + kk];
    a0=fmaf(x0,w.x,a0); a1=fmaf(x0,w.y,a1); a2=fmaf(x0,w.z,a2); a3=fmaf(x0,w.w,a3);
    c0=fmaf(x1,w.x,c0); c1=fmaf(x1,w.y,c1); c2=fmaf(x1,w.z,c2); c3=fmaf(x1,w.w,c3);
  }
  float* rp = &red[kg][cg][0];
  rp[0]=a0; rp[1]=a1; rp[2]=a2; rp[3]=a3; rp[4]=c0; rp[5]=c1; rp[6]=c2; rp[7]=c3;
  __syncthreads();
  int cg2 = tid & 31, q = tid >> 5;
  float s = 0.f;
  #pragma unroll
  for (int g = 0; g < 8; ++g) s += red[g][cg2][q];
  int t = q >> 2, c = q & 3;
  part[(size_t)(t*N + blockIdx.x*128 + cg2*4 + c)*P + blockIdx.y] = s;
}

__global__ void k_red(const float* __restrict__ part, float* __restrict__ outp,
                      int M, int P)
{
  int i = blockIdx.x*256 + threadIdx.x;
  if (i < M) {
    float s = 0.f;
    for (int p = 0; p < P; ++p) s += part[(size_t)i*P + p];
    outp[i] = s;
  }
}

// ---------------------------------------------------------------------------
// U gemm: raw U[ap][n][t] += sum_k relu(sp_pre+b1)[k][t] * gs_w2[k][12n+9+ap],
// and tp_pre[n][ap] += sum_k tp_h[k] * gt_w2[k][12n+9+ap].
// Grid (4,16): 256 nodes/block, 16-k chunks. float4 loads at col 12n+8 (aligned).
__global__ void __launch_bounds__(256) k_U_gemm(
    const float* __restrict__ sp_pre, const float* __restrict__ gs_b1,
    const float* __restrict__ tp_h,
    const float* __restrict__ gs_w2, const float* __restrict__ gt_w2,
    float* __restrict__ U, float* __restrict__ tp_pre)
{
  __shared__ float spl[16*12];
  __shared__ float tpl[16];
  int tid = threadIdx.x;
  int n = blockIdx.x*256 + tid;
  int k0 = blockIdx.y*16;
  if (tid < 192) {
    int kk = tid / 12, bb = tid % 12;
    float v = sp_pre[bb*256 + k0 + kk] + gs_b1[k0 + kk];
    spl[kk*12 + bb] = v > 0.f ? v : 0.f;
  }
  if (tid < 16) tpl[tid] = tp_h[k0 + tid];
  __syncthreads();
  float sA[3][12];
  float tA[3] = {0.f, 0.f, 0.f};
  #pragma unroll
  for (int ap=0;ap<3;++ap)
    #pragma unroll
    for (int t=0;t<12;++t) sA[ap][t]=0.f;
  #pragma unroll
  for (int kk = 0; kk < 16; ++kk) {
    float4 ws4 = *(const float4*)(gs_w2 + (size_t)(k0+kk)*12288 + 12*n + 8);
    float4 wt4 = *(const float4*)(gt_w2 + (size_t)(k0+kk)*12288 + 12*n + 8);
    float w0 = ws4.y, w1 = ws4.z, w2 = ws4.w;
    #pragma unroll
    for (int t=0;t<12;++t) {
      float s = spl[kk*12 + t];
      sA[0][t] = fmaf(s, w0, sA[0][t]);
      sA[1][t] = fmaf(s, w1, sA[1][t]);
      sA[2][t] = fmaf(s, w2, sA[2][t]);
    }
    float tv = tpl[kk];
    tA[0] = fmaf(tv, wt4.y, tA[0]);
    tA[1] = fmaf(tv, wt4.z, tA[1]);
    tA[2] = fmaf(tv, wt4.w, tA[2]);
  }
  #pragma unroll
  for (int ap=0;ap<3;++ap) {
    #pragma unroll
    for (int t=0;t<12;++t)
      atomicAdd(&U[ap*12288 + n*12 + t], sA[ap][t]);
    atomicAdd(&tp_pre[n*3 + ap], tA[ap]);
  }
}

// epilogue: U[i] = relu(U[i]+gs_b2[c]) + relu(tp_pre[n][ap]+gt_b2[c])
__global__ void k_U_epi(float* __restrict__ U, const float* __restrict__ tp_pre,
                        const float* __restrict__ gs_b2, const float* __restrict__ gt_b2)
{
  int i = blockIdx.x*256 + threadIdx.x;   // < 36864
  int ap = i / 12288, rem = i - ap*12288;
  int n = rem / 12, t = rem - n*12;
  (void)t;
  int c = n*12 + 9 + ap;
  float sv = U[i] + gs_b2[c];       sv = sv > 0.f ? sv : 0.f;
  float tv = tp_pre[n*3 + ap] + gt_b2[c]; tv = tv > 0.f ? tv : 0.f;
  U[i] = sv + tv;
}

// ---------------------------------------------------------------------------
// Y precompute: X9/X10 = relu(h3 + b3); three per-node 12x12 products.
__global__ void k_Y(const float* __restrict__ h3, const float* __restrict__ b3,
                    const float* __restrict__ Wf, const float* __restrict__ Wb,
                    float* __restrict__ Y)
{
  __shared__ float Ws0[144], Ws1[144], Ws2[144];
  int tid = threadIdx.x;
  if (tid < 144) {
    Ws0[tid] = Wf[144 + tid];          // Wf[1]       (path 0, L(9,10))
    Ws1[tid] = Wf[tid] + Wb[tid];      // Wf[0]+Wb[0] (path 1, L(10,10))
    Ws2[tid] = Wb[144 + tid];          // Wb[1]       (path 2, L(11,10))
  }
  __syncthreads();
  int n = blockIdx.x*256 + tid;
  float X9[12], X10[12];
  #pragma unroll
  for (int f=0; f<12; ++f) {
    float bb = b3[n*12 + f];
    float v9  = h3[n*12 + f] + bb;          X9[f]  = v9  > 0.f ? v9  : 0.f;
    float v10 = h3[12288 + n*12 + f] + bb;  X10[f] = v10 > 0.f ? v10 : 0.f;
  }
  #pragma unroll
  for (int g=0; g<12; ++g) {
    float y0=0.f, y1=0.f, y2=0.f;
    #pragma unroll
    for (int f=0; f<12; ++f) {
      y0 = fmaf(X9[f],  Ws0[f*12+g], y0);
      y1 = fmaf(X10[f], Ws1[f*12+g], y1);
      y2 = fmaf(X9[f],  Ws2[f*12+g], y2);
    }
    Y[n*12 + g]         = y0;
    Y[12288 + n*12 + g] = y1;
    Y[24576 + n*12 + g] = y2;
  }
}

// ---------------------------------------------------------------------------
// Fused scores -> threshold -> softmax -> weighted sum. TWO rows per block.
#define SS 1032
__global__ void __launch_bounds__(256) k_final(
    const float* __restrict__ U, const float* __restrict__ Y,
    const float* __restrict__ Bm, const float* __restrict__ bvec,
    float* __restrict__ out)
{
  __shared__ float sc[6*SS];
  __shared__ float P[2][3][12];
  __shared__ float invS[6];
  __shared__ float Bl[144];
  __shared__ float bl[12];
  int tid = threadIdx.x;
  int i0 = blockIdx.x*2;
  if (tid < 144) Bl[tid] = Bm[tid];
  if (tid < 12)  bl[tid] = bvec[tid];
  __syncthreads();
  if (tid < 72) {  // P[r][ap][j] = sum_t U[ap][i0+r][t] * B[t][j]
    int r = tid / 36, ap = (tid / 12) % 3, j = tid % 12;
    float s = 0.f;
    #pragma unroll
    for (int t=0;t<12;++t)
      s = fmaf(U[ap*12288 + (i0+r)*12 + t], Bl[t*12 + j], s);
    P[r][ap][j] = s;
  }
  __syncthreads();
  const float* U10 = U + 12288;
  for (int jj = 0; jj < 4; ++jj) {
    int j = tid + jj*256;
    const float4* ur = (const float4*)(U10 + j*12);
    float4 u0 = ur[0], u1 = ur[1], u2 = ur[2];
    float u[12] = {u0.x,u0.y,u0.z,u0.w,u1.x,u1.y,u1.z,u1.w,u2.x,u2.y,u2.z,u2.w};
    #pragma unroll
    for (int r=0;r<2;++r)
      #pragma unroll
      for (int ap=0;ap<3;++ap) {
        float s = 0.f;
        #pragma unroll
        for (int t=0;t<12;++t) s = fmaf(P[r][ap][t], u[t], s);
        sc[(r*3+ap)*SS + j] = (s >= 0.05f) ? s : 0.f;
      }
  }
  __syncthreads();
  int wv = tid >> 6, ln = tid & 63;
  for (int p = wv; p < 6; p += 4) {
    float m = -1e30f;
    for (int q = 0; q < 16; ++q) m = fmaxf(m, sc[p*SS + ln + q*64]);
    #pragma unroll
    for (int o = 32; o > 0; o >>= 1) m = fmaxf(m, __shfl_xor(m, o));
    float sum = 0.f;
    for (int q = 0; q < 16; ++q) {
      int j = ln + q*64;
      float e = __expf(sc[p*SS + j] - m);
      sc[p*SS + j] = e;
      sum += e;
    }
    #pragma unroll
    for (int o = 32; o > 0; o >>= 1) sum += __shfl_xor(sum, o);
    if (ln == 0) invS[p] = 1.f / sum;
  }
  __syncthreads();
  float acc[2][12];
  for (int r = 0; r < 2; ++r)
    for (int f = 0; f < 12; ++f)
      acc[r][f] = 0.f;
  int q3 = tid >> 6, jg = tid & 63;
  if (tid < 192) {   // wave q3 owns Y path q3, both rows
    for (int q = 0; q < 16; ++q) {
      int j = jg + q*64;
      const float4* yr = (const float4*)(Y + q3*12288 + j*12);
      float4 y0 = yr[0], y1 = yr[1], y2 = yr[2];
      float yv[12] = {y0.x,y0.y,y0.z,y0.w,y1.x,y1.y,y1.z,y1.w,y2.x,y2.y,y2.z,y2.w};
      float e0 = sc[(0*3+q3)*SS + j];
      float e1 = sc[(1*3+q3)*SS + j];
      #pragma unroll
      for (int f=0;f<12;++f) {
        acc[0][f] = fmaf(e0, yv[f], acc[0][f]);
        acc[1][f] = fmaf(e1, yv[f], acc[1][f]);
      }
    }
  }
  __syncthreads();  // exps consumed; reuse sc (needs 6*12*64=4608 <= 6*SS)
  float* red = sc;
  if (tid < 192) {
    #pragma unroll
    for (int r=0;r<2;++r)
      #pragma unroll
      for (int f=0;f<12;++f)
        red[((q3*2 + r)*12 + f)*64 + jg] = acc[r][f];
  }
  __syncthreads();
  if (tid < 24) {
    int r = tid / 12, f = tid % 12;
    float s0=0.f, s1=0.f, s2=0.f;
    for (int g = 0; g < 64; ++g) {
      s0 += red[((0*2+r)*12+f)*64 + g];
      s1 += red[((1*2+r)*12+f)*64 + g];
      s2 += red[((2*2+r)*12+f)*64 + g];
    }
    float a1v = invS[r*3+1]*s1;                 // L(10,10) @ X10 @ (Wf0+Wb0)
    float a2v = invS[r*3+0]*s0 + invS[r*3+2]*s2;// L(9,10)@X9@Wf1 + L(11,10)@X9@Wb1
    float v1 = a1v + bl[f]; v1 = v1>0.f ? v1 : 0.f;
    float v2 = a2v + bl[f]; v2 = v2>0.f ? v2 : 0.f;
    out[(i0+r)*12 + f] = v1 + v2;
  }
}

extern "C" void kernel_launch(void* const* d_in, const int* in_sizes, int n_in,
                              void* d_out, int out_size, void* d_ws, size_t ws_size,
                              hipStream_t stream)
{
  const float* obs   = (const float*)d_in[0];
  const float* tf    = (const float*)d_in[1];
  const float* fc_w1 = (const float*)d_in[2];
  const float* fc_b1 = (const float*)d_in[3];
  const float* fc_w2 = (const float*)d_in[4];
  const float* fc_b2 = (const float*)d_in[5];
  const float* fc_w3 = (const float*)d_in[6];
  const float* fc_b3 = (const float*)d_in[7];
  const float* Wf    = (const float*)d_in[8];
  const float* Wb    = (const float*)d_in[9];
  const float* bvec  = (const float*)d_in[10];
  const float* li    = (const float*)d_in[11];
  const float* gs_w1 = (const float*)d_in[12];
  const float* gs_b1 = (const float*)d_in[13];
  const float* gs_w2 = (const float*)d_in[14];
  const float* gs_b2 = (const float*)d_in[15];
  const float* gt_w1 = (const float*)d_in[16];
  const float* gt_b1 = (const float*)d_in[17];
  const float* gt_w2 = (const float*)d_in[18];
  const float* gt_b2 = (const float*)d_in[19];
  const float* Bm    = (const float*)d_in[20];
  float* out = (float*)d_out;
  float* ws  = (float*)d_ws;

  float* obs_ws = ws + OFF_OBS;
  float* sp_pre = ws + OFF_SPPRE;
  float* tp_h   = ws + OFF_TPH;
  float* h1     = ws + OFF_H1;
  float* h2     = ws + OFF_H2;
  float* h3     = ws + OFF_H3;
  float* part   = ws + OFF_PART;
  float* U      = ws + OFF_U;
  float* tp_pre = ws + OFF_TPPRE;
  float* Y      = ws + OFF_Y;

  hipMemsetAsync(d_out, 0, (size_t)out_size * sizeof(float), stream);
  hipMemsetAsync(sp_pre, 0, 3072 * sizeof(float), stream);

  k_hidden<<<dim3(25), dim3(256), 0, stream>>>(li, gs_w1, tf, gt_w1, gt_b1, obs,
                                               obs_ws, sp_pre, tp_h);
  // fc1: (2x8192)@(8192x2048), K split 16x512
  k_gemm2<512><<<dim3(16,16), dim3(256), 0, stream>>>(obs_ws, (const float*)nullptr,
                                                      fc_w1, part, 2048, 8192, 16);
  k_red<<<dim3(16), dim3(256), 0, stream>>>(part, h1, 4096, 16);
  // fc2: (2x2048)@(2048x2048), K split 8x256
  k_gemm2<256><<<dim3(16,8), dim3(256), 0, stream>>>(h1, fc_b1, fc_w2, part,
                                                     2048, 2048, 8);
  k_red<<<dim3(16), dim3(256), 0, stream>>>(part, h2, 4096, 8);
  // fc3: (2x2048)@(2048x12288), K split 2x1024
  k_gemm2<1024><<<dim3(96,2), dim3(256), 0, stream>>>(h2, fc_b2, fc_w3, part,
                                                      12288, 2048, 2);
  k_red<<<dim3(96), dim3(256), 0, stream>>>(part, h3, 24576, 2);

  // part region dead; zero U (36864) + tp_pre (3072) contiguously, then U path
  hipMemsetAsync(U, 0, 39936 * sizeof(float), stream);
  k_U_gemm<<<dim3(4,16), dim3(256), 0, stream>>>(sp_pre, gs_b1, tp_h,
                                                 gs_w2, gt_w2, U, tp_pre);
  k_U_epi<<<dim3(144), dim3(256), 0, stream>>>(U, tp_pre, gs_b2, gt_b2);

  k_Y<<<dim3(4), dim3(256), 0, stream>>>(h3, fc_b3, Wf, Wb, Y);
  k_final<<<dim3(512), dim3(256), 0, stream>>>(U, Y, Bm, bvec, out);
}

// Round 6
// 311.378 us; speedup vs baseline: 1.4441x; 1.2395x over previous
//
#include <hip/hip_runtime.h>

// All tensors float32. ws is huge (~384 MiB per harness poison) — layout is
// generous and non-overlapping, ~6.3 MB total.

// ws layout (float offsets):
#define OFF_OBS   0         // 2x8192 gathered obs rows t=9,10
#define OFF_SPP   16384     // sp partials: [c<16][t<12][col<256]
#define OFF_TPH   65536     // tp hidden (post-relu), 256
#define OFF_P1    65792     // fc1 partials: [(t*2048+col)*16+p]   (65536)
#define OFF_P2    131328    // fc2 partials: [(t*2048+col)*8+p]    (32768)
#define OFF_P3    164096    // fc3 partials: [(t*12288+col)*2+p]   (49152)
#define OFF_UP    213248    // U partials:  [y<32][ap<3][n<1024][t<12] (1179648)
#define OFF_TPP   1392896   // tp2 partials:[y<32][n<1024][ap<3]      (98304)
#define OFF_U     1491200   // U final [ap][n][t] (36864)
#define OFF_Y     1528064   // Y [path][n][g]     (36864)

// ---------------------------------------------------------------------------
// k_hidden: blocks 0..15 sp first-layer partials (2 col-chunks x 8 k-chunks,
// each block's 2 k-halves -> 16 partial chunks, no atomics); block 16 tp
// hidden; blocks 17..24 obs row gather.
__global__ void __launch_bounds__(256) k_hidden(
    const float* __restrict__ li, const float* __restrict__ gs_w1,
    const float* __restrict__ tf, const float* __restrict__ gt_w1,
    const float* __restrict__ gt_b1, const float* __restrict__ obs,
    float* __restrict__ obs_ws, float* __restrict__ sp_part,
    float* __restrict__ tp_h)
{
  int b = blockIdx.x, tid = threadIdx.x;
  if (b < 16) {
    __shared__ float lil[12][128];
    int cb = b & 1, kc = b >> 1;           // col chunk (128), k chunk (128)
    for (int i = tid; i < 1536; i += 256) {
      int bb = i >> 7, kk = i & 127;
      lil[bb][kk] = li[bb*1024 + kc*128 + kk];
    }
    __syncthreads();
    int col = cb*128 + (tid & 127);
    int kh = tid >> 7;                      // k-half of 64
    float acc[12];
    #pragma unroll
    for (int t=0;t<12;++t) acc[t]=0.f;
    for (int kk = kh*64; kk < kh*64 + 64; ++kk) {
      float w = gs_w1[(size_t)(kc*128 + kk)*256 + col];
      #pragma unroll
      for (int t=0;t<12;++t) acc[t] = fmaf(lil[t][kk], w, acc[t]);
    }
    int c = kc*2 + kh;                      // 0..15 partial chunk
    #pragma unroll
    for (int t=0;t<12;++t) sp_part[(c*12 + t)*256 + col] = acc[t];
  } else if (b == 16) {
    float acc = 0.f;
    for (int k = 0; k < 36; ++k)
      acc = fmaf(tf[k], gt_w1[k*256 + tid], acc);
    float v = acc + gt_b1[tid];
    tp_h[tid] = v > 0.f ? v : 0.f;
  } else {
    int g = b - 17;                         // 0..7
    for (int i = tid; i < 2048; i += 256) {
      int e = g*2048 + i;
      int tp = e >> 13, k = e & 8191;
      int n = k >> 3, d = k & 7;
      obs_ws[e] = obs[n*96 + d*12 + 9 + tp];
    }
  }
}

// ---------------------------------------------------------------------------
// 2-row GEMM body, split-K, plain partial stores. Input is either direct
// (PIN==0) or the sum of PIN partials (folds the old k_red into staging).
template<int KS, int PIN, int P>
__device__ __forceinline__ void gemm_body(
    const float* __restrict__ xin, const float* __restrict__ bias_in,
    const float* __restrict__ W, float* __restrict__ part,
    int N, int K, int bx, int by, float* lx, float* red)
{
  int tid = threadIdx.x;
  int k0 = by * KS;
  for (int i = tid; i < 2*KS; i += 256) {
    int t = i / KS, kk = i - t*KS;
    float v;
    if (PIN == 0) {
      v = xin[t*K + k0 + kk];
    } else {
      v = 0.f;
      const float* p0 = xin + (size_t)(t*K + k0 + kk)*PIN;
      #pragma unroll
      for (int p = 0; p < PIN; ++p) v += p0[p];
    }
    if (bias_in) { v += bias_in[k0 + kk]; v = v > 0.f ? v : 0.f; }
    lx[i] = v;
  }
  __syncthreads();
  int kg = tid >> 5, cg = tid & 31;
  int colbase = bx*128 + cg*4;
  float a0=0,a1=0,a2=0,a3=0,c0=0,c1=0,c2=0,c3=0;
  const int ksub = KS/8;
  for (int kk = kg*ksub; kk < kg*ksub + ksub; ++kk) {
    float4 w = *(const float4*)(W + (size_t)(k0+kk)*N + colbase);
    float x0 = lx[kk], x1 = lx[KS + kk];
    a0=fmaf(x0,w.x,a0); a1=fmaf(x0,w.y,a1); a2=fmaf(x0,w.z,a2); a3=fmaf(x0,w.w,a3);
    c0=fmaf(x1,w.x,c0); c1=fmaf(x1,w.y,c1); c2=fmaf(x1,w.z,c2); c3=fmaf(x1,w.w,c3);
  }
  float* rp = red + (kg*32 + cg)*8;
  rp[0]=a0; rp[1]=a1; rp[2]=a2; rp[3]=a3; rp[4]=c0; rp[5]=c1; rp[6]=c2; rp[7]=c3;
  __syncthreads();
  int cg2 = tid & 31, q = tid >> 5;
  float s = 0.f;
  #pragma unroll
  for (int g = 0; g < 8; ++g) s += red[(g*32 + cg2)*8 + q];
  int t = q >> 2, c = q & 3;
  part[(size_t)(t*N + bx*128 + cg2*4 + c)*P + by] = s;
}

template<int KS, int PIN, int P>
__global__ void __launch_bounds__(256) k_gemm(
    const float* __restrict__ xin, const float* __restrict__ bias_in,
    const float* __restrict__ W, float* __restrict__ part, int N, int K)
{
  __shared__ float lx[2*KS];
  __shared__ float red[2048];
  gemm_body<KS, PIN, P>(xin, bias_in, W, part, N, K, blockIdx.x, blockIdx.y,
                        lx, red);
}

// ---------------------------------------------------------------------------
// k_big: blocks 0..191 = fc3 GEMM (96 col-chunks x 2 k-chunks);
// blocks 192..319 = U-GEMM (4 node-groups x 32 k-chunks of 8), partial stores.
__global__ void __launch_bounds__(256) k_big(
    const float* __restrict__ part2, const float* __restrict__ fc_b2,
    const float* __restrict__ fc_w3, float* __restrict__ part3,
    const float* __restrict__ sp_part, const float* __restrict__ gs_b1,
    const float* __restrict__ tp_h,
    const float* __restrict__ gs_w2, const float* __restrict__ gt_w2,
    float* __restrict__ U_part, float* __restrict__ tp_part)
{
  __shared__ float smem[4096];  // gemm: lx(2048)+red(2048); U path: spl/tpl
  int g = blockIdx.x, tid = threadIdx.x;
  if (g < 192) {
    gemm_body<1024, 8, 2>(part2, fc_b2, fc_w3, part3, 12288, 2048,
                          g >> 1, g & 1, smem, smem + 2048);
  } else {
    float* spl = smem;        // 96: relu'd sp hidden [kk<8][t<12]
    float* tpl = smem + 96;   // 8
    int ug = g - 192;
    int n  = (ug & 3)*256 + tid;
    int uy = ug >> 2;
    int k0 = uy*8;
    if (tid < 96) {
      int kk = tid / 12, t = tid % 12;
      float v = gs_b1[k0 + kk];
      #pragma unroll
      for (int c = 0; c < 16; ++c) v += sp_part[(c*12 + t)*256 + k0 + kk];
      spl[kk*12 + t] = v > 0.f ? v : 0.f;
    }
    if (tid < 8) tpl[tid] = tp_h[k0 + tid];
    __syncthreads();
    float sA[3][12];
    float tA[3] = {0.f, 0.f, 0.f};
    #pragma unroll
    for (int ap=0;ap<3;++ap)
      #pragma unroll
      for (int t=0;t<12;++t) sA[ap][t]=0.f;
    #pragma unroll
    for (int kk = 0; kk < 8; ++kk) {
      float4 ws4 = *(const float4*)(gs_w2 + (size_t)(k0+kk)*12288 + 12*n + 8);
      float4 wt4 = *(const float4*)(gt_w2 + (size_t)(k0+kk)*12288 + 12*n + 8);
      float w0 = ws4.y, w1 = ws4.z, w2 = ws4.w;
      #pragma unroll
      for (int t=0;t<12;++t) {
        float s = spl[kk*12 + t];
        sA[0][t] = fmaf(s, w0, sA[0][t]);
        sA[1][t] = fmaf(s, w1, sA[1][t]);
        sA[2][t] = fmaf(s, w2, sA[2][t]);
      }
      float tv = tpl[kk];
      tA[0] = fmaf(tv, wt4.y, tA[0]);
      tA[1] = fmaf(tv, wt4.z, tA[1]);
      tA[2] = fmaf(tv, wt4.w, tA[2]);
    }
    #pragma unroll
    for (int ap=0;ap<3;++ap) {
      #pragma unroll
      for (int t=0;t<12;++t)
        U_part[(size_t)uy*36864 + ap*12288 + n*12 + t] = sA[ap][t];
      tp_part[uy*3072 + n*3 + ap] = tA[ap];
    }
  }
}

// ---------------------------------------------------------------------------
// k_mid: blocks 0..143 finalize U (sum 32 partials + bias/relu epilogue);
// blocks 144..147 compute Y from fc3 partials; blocks 148..291 zero outputs 1..3.
__global__ void __launch_bounds__(256) k_mid(
    const float* __restrict__ U_part, const float* __restrict__ tp_part,
    const float* __restrict__ gs_b2, const float* __restrict__ gt_b2,
    float* __restrict__ U,
    const float* __restrict__ part3, const float* __restrict__ fc_b3,
    const float* __restrict__ Wf, const float* __restrict__ Wb,
    float* __restrict__ Y, float* __restrict__ out_tail)
{
  int b = blockIdx.x, tid = threadIdx.x;
  if (b < 144) {
    int i = b*256 + tid;                    // < 36864
    float us = 0.f;
    for (int y = 0; y < 32; ++y) us += U_part[(size_t)y*36864 + i];
    int ap = i / 12288, rem = i - ap*12288, n = rem / 12;
    float ts = 0.f;
    for (int y = 0; y < 32; ++y) ts += tp_part[y*3072 + n*3 + ap];
    int c = n*12 + 9 + ap;
    float sv = us + gs_b2[c]; sv = sv > 0.f ? sv : 0.f;
    float tv = ts + gt_b2[c]; tv = tv > 0.f ? tv : 0.f;
    U[i] = sv + tv;
  } else if (b < 148) {
    __shared__ float Ws0[144], Ws1[144], Ws2[144];
    if (tid < 144) {
      Ws0[tid] = Wf[144 + tid];          // Wf[1]       (path 0, L(9,10))
      Ws1[tid] = Wf[tid] + Wb[tid];      // Wf[0]+Wb[0] (path 1, L(10,10))
      Ws2[tid] = Wb[144 + tid];          // Wb[1]       (path 2, L(11,10))
    }
    __syncthreads();
    int n = (b - 144)*256 + tid;
    float X9[12], X10[12];
    #pragma unroll
    for (int f=0; f<12; ++f) {
      float bb = fc_b3[n*12 + f];
      float v9  = part3[(size_t)(n*12 + f)*2]         + part3[(size_t)(n*12 + f)*2 + 1]         + bb;
      float v10 = part3[(size_t)(12288 + n*12 + f)*2] + part3[(size_t)(12288 + n*12 + f)*2 + 1] + bb;
      X9[f]  = v9  > 0.f ? v9  : 0.f;
      X10[f] = v10 > 0.f ? v10 : 0.f;
    }
    #pragma unroll
    for (int g2=0; g2<12; ++g2) {
      float y0=0.f, y1=0.f, y2=0.f;
      #pragma unroll
      for (int f=0; f<12; ++f) {
        y0 = fmaf(X9[f],  Ws0[f*12+g2], y0);
        y1 = fmaf(X10[f], Ws1[f*12+g2], y1);
        y2 = fmaf(X9[f],  Ws2[f*12+g2], y2);
      }
      Y[n*12 + g2]         = y0;
      Y[12288 + n*12 + g2] = y1;
      Y[24576 + n*12 + g2] = y2;
    }
  } else {
    int i = (b - 148)*256 + tid;            // < 36864
    out_tail[i] = 0.f;
  }
}

// ---------------------------------------------------------------------------
// Fused scores -> threshold -> softmax -> weighted sum. TWO rows per block.
#define SS 1032
__global__ void __launch_bounds__(256) k_final(
    const float* __restrict__ U, const float* __restrict__ Y,
    const float* __restrict__ Bm, const float* __restrict__ bvec,
    float* __restrict__ out)
{
  __shared__ float sc[6*SS];
  __shared__ float P[2][3][12];
  __shared__ float invS[6];
  __shared__ float Bl[144];
  __shared__ float bl[12];
  int tid = threadIdx.x;
  int i0 = blockIdx.x*2;
  if (tid < 144) Bl[tid] = Bm[tid];
  if (tid < 12)  bl[tid] = bvec[tid];
  __syncthreads();
  if (tid < 72) {
    int r = tid / 36, ap = (tid / 12) % 3, j = tid % 12;
    float s = 0.f;
    #pragma unroll
    for (int t=0;t<12;++t)
      s = fmaf(U[ap*12288 + (i0+r)*12 + t], Bl[t*12 + j], s);
    P[r][ap][j] = s;
  }
  __syncthreads();
  const float* U10 = U + 12288;
  for (int jj = 0; jj < 4; ++jj) {
    int j = tid + jj*256;
    const float4* ur = (const float4*)(U10 + j*12);
    float4 u0 = ur[0], u1 = ur[1], u2 = ur[2];
    float u[12] = {u0.x,u0.y,u0.z,u0.w,u1.x,u1.y,u1.z,u1.w,u2.x,u2.y,u2.z,u2.w};
    #pragma unroll
    for (int r=0;r<2;++r)
      #pragma unroll
      for (int ap=0;ap<3;++ap) {
        float s = 0.f;
        #pragma unroll
        for (int t=0;t<12;++t) s = fmaf(P[r][ap][t], u[t], s);
        sc[(r*3+ap)*SS + j] = (s >= 0.05f) ? s : 0.f;
      }
  }
  __syncthreads();
  int wv = tid >> 6, ln = tid & 63;
  for (int p = wv; p < 6; p += 4) {
    float m = -1e30f;
    for (int q = 0; q < 16; ++q) m = fmaxf(m, sc[p*SS + ln + q*64]);
    #pragma unroll
    for (int o = 32; o > 0; o >>= 1) m = fmaxf(m, __shfl_xor(m, o));
    float sum = 0.f;
    for (int q = 0; q < 16; ++q) {
      int j = ln + q*64;
      float e = __expf(sc[p*SS + j] - m);
      sc[p*SS + j] = e;
      sum += e;
    }
    #pragma unroll
    for (int o = 32; o > 0; o >>= 1) sum += __shfl_xor(sum, o);
    if (ln == 0) invS[p] = 1.f / sum;
  }
  __syncthreads();
  float acc[2][12];
  for (int r = 0; r < 2; ++r)
    for (int f = 0; f < 12; ++f)
      acc[r][f] = 0.f;
  int q3 = tid >> 6, jg = tid & 63;
  if (tid < 192) {
    for (int q = 0; q < 16; ++q) {
      int j = jg + q*64;
      const float4* yr = (const float4*)(Y + q3*12288 + j*12);
      float4 y0 = yr[0], y1 = yr[1], y2 = yr[2];
      float yv[12] = {y0.x,y0.y,y0.z,y0.w,y1.x,y1.y,y1.z,y1.w,y2.x,y2.y,y2.z,y2.w};
      float e0 = sc[(0*3+q3)*SS + j];
      float e1 = sc[(1*3+q3)*SS + j];
      #pragma unroll
      for (int f=0;f<12;++f) {
        acc[0][f] = fmaf(e0, yv[f], acc[0][f]);
        acc[1][f] = fmaf(e1, yv[f], acc[1][f]);
      }
    }
  }
  __syncthreads();
  float* red = sc;
  if (tid < 192) {
    #pragma unroll
    for (int r=0;r<2;++r)
      #pragma unroll
      for (int f=0;f<12;++f)
        red[((q3*2 + r)*12 + f)*64 + jg] = acc[r][f];
  }
  __syncthreads();
  if (tid < 24) {
    int r = tid / 12, f = tid % 12;
    float s0=0.f, s1=0.f, s2=0.f;
    for (int g = 0; g < 64; ++g) {
      s0 += red[((0*2+r)*12+f)*64 + g];
      s1 += red[((1*2+r)*12+f)*64 + g];
      s2 += red[((2*2+r)*12+f)*64 + g];
    }
    float a1v = invS[r*3+1]*s1;
    float a2v = invS[r*3+0]*s0 + invS[r*3+2]*s2;
    float v1 = a1v + bl[f]; v1 = v1>0.f ? v1 : 0.f;
    float v2 = a2v + bl[f]; v2 = v2>0.f ? v2 : 0.f;
    out[(i0+r)*12 + f] = v1 + v2;
  }
}

extern "C" void kernel_launch(void* const* d_in, const int* in_sizes, int n_in,
                              void* d_out, int out_size, void* d_ws, size_t ws_size,
                              hipStream_t stream)
{
  const float* obs   = (const float*)d_in[0];
  const float* tf    = (const float*)d_in[1];
  const float* fc_w1 = (const float*)d_in[2];
  const float* fc_b1 = (const float*)d_in[3];
  const float* fc_w2 = (const float*)d_in[4];
  const float* fc_b2 = (const float*)d_in[5];
  const float* fc_w3 = (const float*)d_in[6];
  const float* fc_b3 = (const float*)d_in[7];
  const float* Wf    = (const float*)d_in[8];
  const float* Wb    = (const float*)d_in[9];
  const float* bvec  = (const float*)d_in[10];
  const float* li    = (const float*)d_in[11];
  const float* gs_w1 = (const float*)d_in[12];
  const float* gs_b1 = (const float*)d_in[13];
  const float* gs_w2 = (const float*)d_in[14];
  const float* gs_b2 = (const float*)d_in[15];
  const float* gt_w1 = (const float*)d_in[16];
  const float* gt_b1 = (const float*)d_in[17];
  const float* gt_w2 = (const float*)d_in[18];
  const float* gt_b2 = (const float*)d_in[19];
  const float* Bm    = (const float*)d_in[20];
  float* out = (float*)d_out;
  float* ws  = (float*)d_ws;

  float* obs_ws  = ws + OFF_OBS;
  float* sp_part = ws + OFF_SPP;
  float* tp_h    = ws + OFF_TPH;
  float* part1   = ws + OFF_P1;
  float* part2   = ws + OFF_P2;
  float* part3   = ws + OFF_P3;
  float* U_part  = ws + OFF_UP;
  float* tp_part = ws + OFF_TPP;
  float* U       = ws + OFF_U;
  float* Y       = ws + OFF_Y;

  k_hidden<<<dim3(25), dim3(256), 0, stream>>>(li, gs_w1, tf, gt_w1, gt_b1, obs,
                                               obs_ws, sp_part, tp_h);
  // fc1: (2x8192)@(8192x2048), K split 16x512, direct input
  k_gemm<512, 0, 16><<<dim3(16,16), dim3(256), 0, stream>>>(
      obs_ws, (const float*)nullptr, fc_w1, part1, 2048, 8192);
  // fc2: (2x2048)@(2048x2048), K split 8x256, input = sum of 16 fc1 partials
  k_gemm<256, 16, 8><<<dim3(16,8), dim3(256), 0, stream>>>(
      part1, fc_b1, fc_w2, part2, 2048, 2048);
  // fc3 (96x2 blocks) + U-GEMM (128 blocks) fused
  k_big<<<dim3(320), dim3(256), 0, stream>>>(part2, fc_b2, fc_w3, part3,
                                             sp_part, gs_b1, tp_h,
                                             gs_w2, gt_w2, U_part, tp_part);
  // U finalize + Y + zero outputs 1..3
  k_mid<<<dim3(292), dim3(256), 0, stream>>>(U_part, tp_part, gs_b2, gt_b2, U,
                                             part3, fc_b3, Wf, Wb, Y,
                                             out + 12288);
  k_final<<<dim3(512), dim3(256), 0, stream>>>(U, Y, Bm, bvec, out);
}